// Round 1
// baseline (137.442 us; speedup 1.0000x reference)
//
#include <hip/hip_runtime.h>

// Problem constants
#define BB 1024      // batch
#define CC 1000      // classes
#define KK 4         // centers per class
#define DD 1024      // feature dim
#define MC 4000      // C*K
#define MCP 4096     // padded MC
#define SIGMA_INV (1.0f/10.0f)

typedef __attribute__((ext_vector_type(8))) short bf16x8;
typedef __attribute__((ext_vector_type(4))) float f32x4;

#define GLDS16(g, l) __builtin_amdgcn_global_load_lds( \
    (const __attribute__((address_space(1))) void*)(g), \
    (__attribute__((address_space(3))) void*)(l), 16, 0, 0)

__device__ __forceinline__ unsigned short f2bf(float x) {
  unsigned u = __float_as_uint(x);
  unsigned r = (u + 0x7fffu + ((u >> 16) & 1u)) >> 16;
  return (unsigned short)r;
}

// ---------------- prep: fp32 -> bf16, row sums of squares, zero accumulators ---
__global__ __launch_bounds__(256) void prep_kernel(
    const float* __restrict__ f, const float* __restrict__ centers,
    unsigned short* __restrict__ fbf, unsigned short* __restrict__ wbf,
    float* __restrict__ f_sq, float* __restrict__ w_sq,
    double* __restrict__ acc2)
{
  if (blockIdx.x == 0 && threadIdx.x == 0) { acc2[0] = 0.0; acc2[1] = 0.0; }
  const int wv = threadIdx.x >> 6, lane = threadIdx.x & 63;
  const int row = blockIdx.x * 4 + wv;            // 0..5119
  const float* src = nullptr;
  unsigned short* dst;
  float* sqp;
  if (row < BB) {
    src = f + (size_t)row * DD; dst = fbf + (size_t)row * DD; sqp = f_sq + row;
  } else {
    int wr = row - BB;                             // 0..4095
    dst = wbf + (size_t)wr * DD; sqp = w_sq + wr;
    if (wr < MC) src = centers + (size_t)wr * DD;
  }
  float ssum = 0.f;
#pragma unroll
  for (int p = 0; p < 4; ++p) {
    int idx = p * 256 + lane * 4;
    float4 v = make_float4(0.f, 0.f, 0.f, 0.f);
    if (src) v = *(const float4*)(src + idx);
    ssum += v.x * v.x + v.y * v.y + v.z * v.z + v.w * v.w;
    ushort4 o;
    o.x = f2bf(v.x); o.y = f2bf(v.y); o.z = f2bf(v.z); o.w = f2bf(v.w);
    *(ushort4*)(dst + idx) = o;
  }
#pragma unroll
  for (int s = 32; s; s >>= 1) ssum += __shfl_xor(ssum, s);
  if (lane == 0) *sqp = ssum;
}

// ---------------- shared GEMM tile core (128x128, BK=64, 4 waves) -------------
// LDS layout: [row][slot] with slot = chunk ^ (row&7), chunk/slot are 8-bf16 (16B)
// units. global_load_lds writes linearly; source address pre-applies the inverse
// swizzle; ds_read applies the same XOR. (both-sides rule)

__device__ __forceinline__ void stage_tile(
    const unsigned short* __restrict__ gbase, size_t row0, int k0,
    unsigned short* lds, int tid)
{
#pragma unroll
  for (int i = 0; i < 4; ++i) {
    int idx = i * 256 + tid;
    int drow = idx >> 3, dslot = idx & 7;
    int schunk = dslot ^ (drow & 7);
    GLDS16(gbase + (row0 + (size_t)drow) * DD + k0 + schunk * 8, &lds[idx * 8]);
  }
}

// ---------------- fw kernel: distance[b][c] -----------------------------------
__global__ __launch_bounds__(256, 2) void fw_kernel(
    const unsigned short* __restrict__ fbf, const unsigned short* __restrict__ wbf,
    const float* __restrict__ f_sq, const float* __restrict__ w_sq,
    float* __restrict__ out)
{
  __shared__ __align__(16) unsigned short As[128 * 64];
  __shared__ __align__(16) unsigned short Bs[128 * 64];
  const int tid = threadIdx.x;
  const int lane = tid & 63, wv = tid >> 6;
  const int wr = wv >> 1, wc = wv & 1;
  const int tr = blockIdx.x, tc = blockIdx.y;    // tr<8 (B), tc<32 (mc)

  f32x4 acc[4][4] = {};
  const int rlo = lane & 15, rhi = lane >> 4, rx = lane & 7;

  for (int kt = 0; kt < DD / 64; ++kt) {
    stage_tile(fbf, (size_t)tr * 128, kt * 64, As, tid);
    stage_tile(wbf, (size_t)tc * 128, kt * 64, Bs, tid);
    __syncthreads();
#pragma unroll
    for (int kk = 0; kk < 2; ++kk) {
      bf16x8 af[4], bw[4];
#pragma unroll
      for (int m = 0; m < 4; ++m) {
        int row = wr * 64 + m * 16 + rlo;
        int slot = (kk * 4 + rhi) ^ rx;
        af[m] = *(const bf16x8*)&As[row * 64 + slot * 8];
      }
#pragma unroll
      for (int n = 0; n < 4; ++n) {
        int row = wc * 64 + n * 16 + rlo;
        int slot = (kk * 4 + rhi) ^ rx;
        bw[n] = *(const bf16x8*)&Bs[row * 64 + slot * 8];
      }
#pragma unroll
      for (int m = 0; m < 4; ++m)
#pragma unroll
        for (int n = 0; n < 4; ++n)
          acc[m][n] = __builtin_amdgcn_mfma_f32_16x16x32_bf16(af[m], bw[n], acc[m][n], 0, 0, 0);
    }
    __syncthreads();
  }

  // epilogue: dist = exp(-max(f_sq + w_sq - 2fw, 0)/sigma), max over quads of 4 cols
#pragma unroll
  for (int m = 0; m < 4; ++m) {
    int row = tr * 128 + wr * 64 + m * 16 + rhi * 4;
#pragma unroll
    for (int n = 0; n < 4; ++n) {
      int col = tc * 128 + wc * 64 + n * 16 + rlo;
      float wsq = w_sq[col];
#pragma unroll
      for (int r = 0; r < 4; ++r) {
        float fn = f_sq[row + r] + wsq - 2.0f * acc[m][n][r];
        fn = fmaxf(fn, 0.f);
        float dist = __expf(-fn * SIGMA_INV);
        dist = fmaxf(dist, __shfl_xor(dist, 1));
        dist = fmaxf(dist, __shfl_xor(dist, 2));
        if ((lane & 3) == 0 && col < MC)
          out[(size_t)(row + r) * (CC + 1) + (col >> 2)] = dist;
      }
    }
  }
}

// ---------------- ww kernel: upper-triangle stats of pairwise distances -------
__global__ __launch_bounds__(256, 2) void ww_kernel(
    const unsigned short* __restrict__ wbf, const float* __restrict__ w_sq,
    double* __restrict__ acc2)
{
  const int tr = blockIdx.x, tc = blockIdx.y;    // 32x32, keep tc>=tr
  if (tc < tr) return;
  __shared__ __align__(16) unsigned short As[128 * 64];
  __shared__ __align__(16) unsigned short Bs[128 * 64];
  __shared__ double rbuf[8];
  const int tid = threadIdx.x;
  const int lane = tid & 63, wv = tid >> 6;
  const int wr = wv >> 1, wc = wv & 1;

  f32x4 acc[4][4] = {};
  const int rlo = lane & 15, rhi = lane >> 4, rx = lane & 7;

  for (int kt = 0; kt < DD / 64; ++kt) {
    stage_tile(wbf, (size_t)tr * 128, kt * 64, As, tid);
    stage_tile(wbf, (size_t)tc * 128, kt * 64, Bs, tid);
    __syncthreads();
#pragma unroll
    for (int kk = 0; kk < 2; ++kk) {
      bf16x8 af[4], bw[4];
#pragma unroll
      for (int m = 0; m < 4; ++m) {
        int row = wr * 64 + m * 16 + rlo;
        int slot = (kk * 4 + rhi) ^ rx;
        af[m] = *(const bf16x8*)&As[row * 64 + slot * 8];
      }
#pragma unroll
      for (int n = 0; n < 4; ++n) {
        int row = wc * 64 + n * 16 + rlo;
        int slot = (kk * 4 + rhi) ^ rx;
        bw[n] = *(const bf16x8*)&Bs[row * 64 + slot * 8];
      }
#pragma unroll
      for (int m = 0; m < 4; ++m)
#pragma unroll
        for (int n = 0; n < 4; ++n)
          acc[m][n] = __builtin_amdgcn_mfma_f32_16x16x32_bf16(af[m], bw[n], acc[m][n], 0, 0, 0);
    }
    __syncthreads();
  }

  double s1 = 0.0, s2 = 0.0;   // sum(s), sum((s-1)^2) over valid i<=j pairs
#pragma unroll
  for (int m = 0; m < 4; ++m) {
    int i0 = tr * 128 + wr * 64 + m * 16 + rhi * 4;
#pragma unroll
    for (int n = 0; n < 4; ++n) {
      int j = tc * 128 + wc * 64 + n * 16 + rlo;
      float wsqj = (j < MC) ? w_sq[j] : 0.f;
#pragma unroll
      for (int r = 0; r < 4; ++r) {
        int i = i0 + r;
        if (i < MC && j < MC && j >= i) {
          float s = fmaxf(w_sq[i] + wsqj - 2.0f * acc[m][n][r], 0.f);
          s1 += (double)s;
          double d = (double)s - 1.0;
          s2 += d * d;
        }
      }
    }
  }
#pragma unroll
  for (int s = 32; s; s >>= 1) { s1 += __shfl_xor(s1, s); s2 += __shfl_xor(s2, s); }
  if (lane == 0) { rbuf[wv * 2] = s1; rbuf[wv * 2 + 1] = s2; }
  __syncthreads();
  if (tid == 0) {
    atomicAdd(&acc2[0], rbuf[0] + rbuf[2] + rbuf[4] + rbuf[6]);
    atomicAdd(&acc2[1], rbuf[1] + rbuf[3] + rbuf[5] + rbuf[7]);
  }
}

// ---------------- finalize: rw scalar + broadcast to out[:,C] -----------------
__global__ __launch_bounds__(256) void finalize_kernel(
    const double* __restrict__ acc2, float* __restrict__ out)
{
  __shared__ float rws;
  if (threadIdx.x == 0) {
    double SS1 = acc2[0], SS2 = acc2[1];
    double denom = 2.0 / ((double)MC * (double)MC - (double)MC);
    double mu = denom * SS1;
    double T = (double)MC * (double)(MC + 1) * 0.5;
    double sm1 = SS1 - T;                 // sum(s - 1)
    double dm = mu - 1.0;
    double resid = SS2 - 2.0 * dm * sm1 + T * dm * dm;
    rws = (float)(denom * resid);
  }
  __syncthreads();
  float v = rws;
  for (int b = threadIdx.x; b < BB; b += 256)
    out[(size_t)b * (CC + 1) + CC] = v;
}

// ---------------- launch ------------------------------------------------------
extern "C" void kernel_launch(void* const* d_in, const int* in_sizes, int n_in,
                              void* d_out, int out_size, void* d_ws, size_t ws_size,
                              hipStream_t stream) {
  const float* f = (const float*)d_in[0];
  const float* centers = (const float*)d_in[1];
  float* out = (float*)d_out;
  char* ws = (char*)d_ws;

  double* acc2        = (double*)(ws + 0);
  float* f_sq         = (float*)(ws + 4096);
  float* w_sq         = (float*)(ws + 8192);           // MCP floats
  unsigned short* fbf = (unsigned short*)(ws + 24576); // BB*DD bf16 = 2MB
  unsigned short* wbf = (unsigned short*)(ws + 24576 + 2 * 1024 * 1024); // MCP*DD bf16 = 8MB

  prep_kernel<<<(BB + MCP) / 4, 256, 0, stream>>>(f, centers, fbf, wbf, f_sq, w_sq, acc2);
  fw_kernel<<<dim3(BB / 128, MCP / 128), 256, 0, stream>>>(fbf, wbf, f_sq, w_sq, out);
  ww_kernel<<<dim3(MCP / 128, MCP / 128), 256, 0, stream>>>(wbf, w_sq, acc2);
  finalize_kernel<<<1, 256, 0, stream>>>(acc2, out);
}

// Round 2
// 114.097 us; speedup vs baseline: 1.2046x; 1.2046x over previous
//
#include <hip/hip_runtime.h>

// Problem constants
#define BB 1024      // batch
#define CC 1000      // classes
#define DD 1024      // feature dim
#define MC 4000      // C*K
#define MCP 4096     // padded MC
#define SIGMA_INV (1.0f/10.0f)

typedef __attribute__((ext_vector_type(8))) short bf16x8;
typedef __attribute__((ext_vector_type(4))) float f32x4;

#define GLDS16(g, l) __builtin_amdgcn_global_load_lds( \
    (const __attribute__((address_space(1))) void*)(g), \
    (__attribute__((address_space(3))) void*)(l), 16, 0, 0)

__device__ __forceinline__ unsigned short f2bf(float x) {
  unsigned u = __float_as_uint(x);
  unsigned r = (u + 0x7fffu + ((u >> 16) & 1u)) >> 16;
  return (unsigned short)r;
}

// ---------------- prep: fp32 -> bf16, row sums of squares, zero accumulators ---
__global__ __launch_bounds__(256) void prep_kernel(
    const float* __restrict__ f, const float* __restrict__ centers,
    unsigned short* __restrict__ fbf, unsigned short* __restrict__ wbf,
    float* __restrict__ f_sq, float* __restrict__ w_sq,
    double* __restrict__ acc2)
{
  if (blockIdx.x == 0 && threadIdx.x == 0) { acc2[0] = 0.0; acc2[1] = 0.0; }
  const int wv = threadIdx.x >> 6, lane = threadIdx.x & 63;
  const int row = blockIdx.x * 4 + wv;            // 0..5119
  const float* src = nullptr;
  unsigned short* dst;
  float* sqp;
  if (row < BB) {
    src = f + (size_t)row * DD; dst = fbf + (size_t)row * DD; sqp = f_sq + row;
  } else {
    int wr = row - BB;                             // 0..4095
    dst = wbf + (size_t)wr * DD; sqp = w_sq + wr;
    if (wr < MC) src = centers + (size_t)wr * DD;
  }
  float ssum = 0.f;
#pragma unroll
  for (int p = 0; p < 4; ++p) {
    int idx = p * 256 + lane * 4;
    float4 v = make_float4(0.f, 0.f, 0.f, 0.f);
    if (src) v = *(const float4*)(src + idx);
    ssum += v.x * v.x + v.y * v.y + v.z * v.z + v.w * v.w;
    ushort4 o;
    o.x = f2bf(v.x); o.y = f2bf(v.y); o.z = f2bf(v.z); o.w = f2bf(v.w);
    *(ushort4*)(dst + idx) = o;
  }
#pragma unroll
  for (int s = 32; s; s >>= 1) ssum += __shfl_xor(ssum, s);
  if (lane == 0) *sqp = ssum;
}

// ---------------- staging: 128x64 bf16 tile, XOR-swizzled (both-sides) --------
// LDS layout: [row][slot], slot = chunk ^ (row&7), chunk/slot = 8-bf16 (16B)
// units. global_load_lds writes linearly; the global source pre-applies the
// inverse swizzle; ds_read applies the same XOR.
__device__ __forceinline__ void stage_tile(
    const unsigned short* __restrict__ gbase, size_t row0, int k0,
    unsigned short* lds, int tid)
{
#pragma unroll
  for (int i = 0; i < 4; ++i) {
    int idx = i * 256 + tid;
    int drow = idx >> 3, dslot = idx & 7;
    int schunk = dslot ^ (drow & 7);
    GLDS16(gbase + (row0 + (size_t)drow) * DD + k0 + schunk * 8, &lds[idx * 8]);
  }
}

// ---------------- unified GEMM: 256 fw tiles + 528 ww triangle tiles ----------
// grid = 784 = 8 * 98 (bijective XCD swizzle). 128x128 tile, BK=64, 4 waves.
__global__ __launch_bounds__(256, 3) void gemm_kernel(
    const unsigned short* __restrict__ fbf, const unsigned short* __restrict__ wbf,
    const float* __restrict__ f_sq, const float* __restrict__ w_sq,
    float* __restrict__ out, double* __restrict__ acc2)
{
  __shared__ __align__(16) unsigned short As[128 * 64];
  __shared__ __align__(16) unsigned short Bs[128 * 64];
  __shared__ double rbuf[8];

  const int orig = blockIdx.x;
  const int bid = (orig & 7) * 98 + (orig >> 3);   // XCD-chunked, bijective (784%8==0)
  const bool is_fw = bid < 256;
  int tr, tc;
  const unsigned short* Abase;
  if (is_fw) {
    tr = bid >> 5; tc = bid & 31;                  // 8 x 32
    Abase = fbf;
  } else {
    int t = bid - 256;                             // 0..527 upper triangle of 32x32
    tr = 0;
    while (t >= 32 - tr) { t -= 32 - tr; ++tr; }
    tc = tr + t;                                   // tc >= tr
    Abase = wbf;
  }

  const int tid = threadIdx.x;
  const int lane = tid & 63, wv = tid >> 6;
  const int wr = wv >> 1, wc = wv & 1;
  const int rlo = lane & 15, rhi = lane >> 4, rx = lane & 7;

  f32x4 acc[4][4] = {};

  for (int kt = 0; kt < DD / 64; ++kt) {
    stage_tile(Abase, (size_t)tr * 128, kt * 64, As, tid);
    stage_tile(wbf,  (size_t)tc * 128, kt * 64, Bs, tid);
    __syncthreads();
#pragma unroll
    for (int kk = 0; kk < 2; ++kk) {
      bf16x8 af[4], bw[4];
#pragma unroll
      for (int m = 0; m < 4; ++m) {
        int row = wr * 64 + m * 16 + rlo;
        int slot = (kk * 4 + rhi) ^ rx;
        af[m] = *(const bf16x8*)&As[row * 64 + slot * 8];
      }
#pragma unroll
      for (int n = 0; n < 4; ++n) {
        int row = wc * 64 + n * 16 + rlo;
        int slot = (kk * 4 + rhi) ^ rx;
        bw[n] = *(const bf16x8*)&Bs[row * 64 + slot * 8];
      }
#pragma unroll
      for (int m = 0; m < 4; ++m)
#pragma unroll
        for (int n = 0; n < 4; ++n)
          acc[m][n] = __builtin_amdgcn_mfma_f32_16x16x32_bf16(af[m], bw[n], acc[m][n], 0, 0, 0);
    }
    __syncthreads();
  }

  if (is_fw) {
    // dist = exp(-max(f_sq + w_sq - 2fw, 0)/sigma), max over quads of 4 cols
#pragma unroll
    for (int m = 0; m < 4; ++m) {
      int row = tr * 128 + wr * 64 + m * 16 + rhi * 4;
#pragma unroll
      for (int n = 0; n < 4; ++n) {
        int col = tc * 128 + wc * 64 + n * 16 + rlo;
        float wsq = w_sq[col];
#pragma unroll
        for (int r = 0; r < 4; ++r) {
          float fn = f_sq[row + r] + wsq - 2.0f * acc[m][n][r];
          fn = fmaxf(fn, 0.f);
          float dist = __expf(-fn * SIGMA_INV);
          dist = fmaxf(dist, __shfl_xor(dist, 1));
          dist = fmaxf(dist, __shfl_xor(dist, 2));
          if ((lane & 3) == 0 && col < MC)
            out[(size_t)(row + r) * (CC + 1) + (col >> 2)] = dist;
        }
      }
    }
  } else {
    // upper-triangle stats: s1 = sum(s), s2 = sum((s-1)^2), i<=j only
    double s1 = 0.0, s2 = 0.0;
#pragma unroll
    for (int m = 0; m < 4; ++m) {
      int i0 = tr * 128 + wr * 64 + m * 16 + rhi * 4;
#pragma unroll
      for (int n = 0; n < 4; ++n) {
        int j = tc * 128 + wc * 64 + n * 16 + rlo;
        float wsqj = (j < MC) ? w_sq[j] : 0.f;
#pragma unroll
        for (int r = 0; r < 4; ++r) {
          int i = i0 + r;
          if (i < MC && j < MC && j >= i) {
            float s = fmaxf(w_sq[i] + wsqj - 2.0f * acc[m][n][r], 0.f);
            s1 += (double)s;
            double d = (double)s - 1.0;
            s2 += d * d;
          }
        }
      }
    }
#pragma unroll
    for (int s = 32; s; s >>= 1) { s1 += __shfl_xor(s1, s); s2 += __shfl_xor(s2, s); }
    if (lane == 0) { rbuf[wv * 2] = s1; rbuf[wv * 2 + 1] = s2; }
    __syncthreads();
    if (tid == 0) {
      atomicAdd(&acc2[0], rbuf[0] + rbuf[2] + rbuf[4] + rbuf[6]);
      atomicAdd(&acc2[1], rbuf[1] + rbuf[3] + rbuf[5] + rbuf[7]);
    }
  }
}

// ---------------- finalize: rw scalar + broadcast to out[:,C] -----------------
__global__ __launch_bounds__(256) void finalize_kernel(
    const double* __restrict__ acc2, float* __restrict__ out)
{
  __shared__ float rws;
  if (threadIdx.x == 0) {
    double SS1 = acc2[0], SS2 = acc2[1];
    double denom = 2.0 / ((double)MC * (double)MC - (double)MC);
    double mu = denom * SS1;
    double T = (double)MC * (double)(MC + 1) * 0.5;  // count of i<=j pairs
    double sm1 = SS1 - T;                 // sum(s - 1)
    double dm = mu - 1.0;
    double resid = SS2 - 2.0 * dm * sm1 + T * dm * dm;
    rws = (float)(denom * resid);
  }
  __syncthreads();
  float v = rws;
  for (int b = threadIdx.x; b < BB; b += 256)
    out[(size_t)b * (CC + 1) + CC] = v;
}

// ---------------- launch ------------------------------------------------------
extern "C" void kernel_launch(void* const* d_in, const int* in_sizes, int n_in,
                              void* d_out, int out_size, void* d_ws, size_t ws_size,
                              hipStream_t stream) {
  const float* f = (const float*)d_in[0];
  const float* centers = (const float*)d_in[1];
  float* out = (float*)d_out;
  char* ws = (char*)d_ws;

  double* acc2        = (double*)(ws + 0);
  float* f_sq         = (float*)(ws + 4096);
  float* w_sq         = (float*)(ws + 8192);           // MCP floats
  unsigned short* fbf = (unsigned short*)(ws + 24576); // BB*DD bf16 = 2MB
  unsigned short* wbf = (unsigned short*)(ws + 24576 + 2 * 1024 * 1024); // MCP*DD bf16 = 8MB

  prep_kernel<<<(BB + MCP) / 4, 256, 0, stream>>>(f, centers, fbf, wbf, f_sq, w_sq, acc2);
  gemm_kernel<<<784, 256, 0, stream>>>(fbf, wbf, f_sq, w_sq, out, acc2);
  finalize_kernel<<<1, 256, 0, stream>>>(acc2, out);
}